// Round 6
// baseline (403.539 us; speedup 1.0000x reference)
//
#include <hip/hip_runtime.h>

#define NTOT 65472
#define NPAD 65536
#define NIMG 4
#define PRE_NMS 1000
#define POST_NMS 300

typedef unsigned long long u64;

// ---------------------------------------------------------------------------
// Kernel 1: decode. One thread per (image, padded anchor).
// key = (~orderable(score) << 32) | anchor_idx  -> ascending = score desc, idx asc
// ---------------------------------------------------------------------------
__global__ __launch_bounds__(256) void k_decode(
    const float* __restrict__ b0, const float* __restrict__ s0, const float* __restrict__ r0,
    const float* __restrict__ b1, const float* __restrict__ s1, const float* __restrict__ r1,
    const float* __restrict__ b2, const float* __restrict__ s2, const float* __restrict__ r2,
    const float* __restrict__ b3, const float* __restrict__ s3, const float* __restrict__ r3,
    const float* __restrict__ b4, const float* __restrict__ s4, const float* __restrict__ r4,
    float* __restrict__ dec_boxes, int* __restrict__ labels, u64* __restrict__ keys)
{
    int gid = blockIdx.x * 256 + threadIdx.x;   // 0 .. 4*65536
    int img = gid >> 16;
    int a   = gid & 0xFFFF;
    if (a >= NTOT) { keys[gid] = ~0ull; return; }

    const float *bp, *sp, *rp; int la, nl;
    if (a < 49152)      { bp=b0; sp=s0; rp=r0; la=a;        nl=49152; }
    else if (a < 61440) { bp=b1; sp=s1; rp=r1; la=a-49152;  nl=12288; }
    else if (a < 64512) { bp=b2; sp=s2; rp=r2; la=a-61440;  nl=3072;  }
    else if (a < 65280) { bp=b3; sp=s3; rp=r3; la=a-64512;  nl=768;   }
    else                { bp=b4; sp=s4; rp=r4; la=a-65280;  nl=192;   }

    size_t row = (size_t)img * nl + la;

    // max/argmax over classes 1..79 (class 0 = background, masked to -inf).
    const float4* s4v = (const float4*)(sp + row * 80);
    float best; int lab;
    {
        float4 v = s4v[0];
        best = v.y; lab = 1;
        if (v.z > best) { best = v.z; lab = 2; }
        if (v.w > best) { best = v.w; lab = 3; }
    }
#pragma unroll
    for (int q = 1; q < 20; q++) {
        float4 v = s4v[q];
        int c = q * 4;
        if (v.x > best) { best = v.x; lab = c;     }
        if (v.y > best) { best = v.y; lab = c + 1; }
        if (v.z > best) { best = v.z; lab = c + 2; }
        if (v.w > best) { best = v.w; lab = c + 3; }
    }

    float4 bx = ((const float4*)bp)[row];
    float4 rg = ((const float4*)rp)[row];
    float x1 = bx.x, y1 = bx.y, x2 = bx.z, y2 = bx.w;
    float w = x2 - x1, h = y2 - y1;
    float cx = x1 + 0.5f * w, cy = y1 + 0.5f * h;
    float dx = rg.x * 0.1f, dy = rg.y * 0.1f, dw = rg.z * 0.2f, dh = rg.w * 0.2f;
    float pcx = dx * w + cx, pcy = dy * h + cy;
    float pw = expf(dw) * w, ph = expf(dh) * h;
    float nx1 = pcx - 0.5f * pw, ny1 = pcy - 0.5f * ph;
    float nx2 = pcx + 0.5f * pw, ny2 = pcy + 0.5f * ph;
    nx1 = fminf(fmaxf(nx1, 0.0f), 1024.0f);
    ny1 = fminf(fmaxf(ny1, 0.0f), 1024.0f);
    nx2 = fminf(fmaxf(nx2, 0.0f), 1024.0f);
    ny2 = fminf(fmaxf(ny2, 0.0f), 1024.0f);
    float wc = nx2 - nx1, hc = ny2 - ny1;
    bool valid = (best > 0.05f) && (wc >= 2.0f) && (hc >= 2.0f);
    float ns = valid ? best : -1.0f;

    size_t gi = (size_t)img * NTOT + a;
    ((float4*)dec_boxes)[gi] = make_float4(nx1, ny1, nx2, ny2);
    labels[gi] = lab;

    unsigned u = __float_as_uint(ns);
    unsigned ord = (u & 0x80000000u) ? ~u : (u | 0x80000000u);
    unsigned d = ~ord;
    keys[gid] = ((u64)d << 32) | (unsigned)a;
}

// ---------------------------------------------------------------------------
// Kernel 2: 4-way sort/merge block. Loads 4 consecutive 1024-key lists
// (32KB LDS). If doSort: bitonic-sorts each 1024-chunk ascending (all 4 in
// parallel). Then pairwise keep-best-1024 merges (0,1) and (2,3) in parallel,
// then final merge -> top-1024 sorted, written out.
// Keys are distinct, so any correct top-1024-sorted reduction is bit-exact.
// ---------------------------------------------------------------------------
__global__ __launch_bounds__(256) void k_sortmerge4(const u64* __restrict__ in,
                                                    u64* __restrict__ out,
                                                    int blocksPerImg, int doSort)
{
    __shared__ u64 s[4096];
    int img = blockIdx.x / blocksPerImg;
    int p   = blockIdx.x % blocksPerImg;
    const u64* src = in + (size_t)img * blocksPerImg * 4096 + (size_t)p * 4096;
    for (int i = threadIdx.x; i < 4096; i += 256) s[i] = src[i];
    __syncthreads();

    if (doSort) {
        for (int k = 2; k <= 1024; k <<= 1) {
            for (int j = k >> 1; j > 0; j >>= 1) {
                for (int t = threadIdx.x; t < 4096; t += 256) {
                    int ch  = t & ~1023;      // chunk base: 0,1024,2048,3072
                    int pos = t & 1023;
                    int l = pos ^ j;
                    if (l > pos) {
                        u64 x = s[ch + pos], y = s[ch + l];
                        bool up = (pos & k) == 0;
                        if (up ? (x > y) : (x < y)) { s[ch + pos] = y; s[ch + l] = x; }
                    }
                }
                __syncthreads();
            }
        }
    }

    // --- pairwise merges (0,1)->[0..1023], (2,3)->[2048..3071], in parallel ---
    // reverse the upper list of each pair (make each 2048-region bitonic)
    for (int t = threadIdx.x; t < 1024; t += 256) {
        int r = (t >> 9) * 2048;              // 0 or 2048
        int i = t & 511;
        u64 a = s[r + 1024 + i], b = s[r + 2047 - i];
        s[r + 1024 + i] = b; s[r + 2047 - i] = a;
    }
    __syncthreads();
    // min phase: keep best 1024 of each region in its lower half
    for (int t = threadIdx.x; t < 2048; t += 256) {
        int r = (t >> 10) * 2048;
        int i = t & 1023;
        u64 x = s[r + i], y = s[r + i + 1024];
        s[r + i] = (x < y) ? x : y;
    }
    __syncthreads();
    // bitonic-clean the lower 1024 of each region, ascending
    for (int j = 512; j > 0; j >>= 1) {
        for (int t = threadIdx.x; t < 2048; t += 256) {
            int r = (t >> 10) * 2048;
            int i = t & 1023;
            int l = i ^ j;
            if (l > i) {
                u64 x = s[r + i], y = s[r + l];
                if (x > y) { s[r + i] = y; s[r + l] = x; }
            }
        }
        __syncthreads();
    }

    // --- final merge: M1 at [0..1023], M2 at [2048..3071] ---
    for (int t = threadIdx.x; t < 1024; t += 256)
        s[1024 + t] = s[2048 + 1023 - t];     // reversed copy of M2
    __syncthreads();
    for (int t = threadIdx.x; t < 1024; t += 256) {
        u64 x = s[t], y = s[t + 1024];
        s[t] = (x < y) ? x : y;
    }
    __syncthreads();
    for (int j = 512; j > 0; j >>= 1) {
        for (int t = threadIdx.x; t < 1024; t += 256) {
            int l = t ^ j;
            if (l > t) {
                u64 x = s[t], y = s[l];
                if (x > y) { s[t] = y; s[l] = x; }
            }
        }
        __syncthreads();
    }

    u64* dst = out + (size_t)img * blocksPerImg * 1024 + (size_t)p * 1024;
    for (int i = threadIdx.x; i < 1024; i += 256) dst[i] = s[i];
}

// ---------------------------------------------------------------------------
// Kernel 3: gather top-1000 (sorted) boxes/scores/labels. keys stride 1024/img.
// ---------------------------------------------------------------------------
__global__ __launch_bounds__(256) void k_gather(const u64* __restrict__ keys,
                                                const float* __restrict__ dec_boxes,
                                                const int* __restrict__ labels,
                                                float* __restrict__ sel_boxes,
                                                float* __restrict__ sel_scores,
                                                int* __restrict__ sel_labels)
{
    int img = blockIdx.x;
    const u64* list = keys + (size_t)img * 1024;
    for (int r = threadIdx.x; r < PRE_NMS; r += 256) {
        u64 k = list[r];
        unsigned d = (unsigned)(k >> 32);
        unsigned idx = (unsigned)(k & 0xFFFFFFFFu);
        unsigned ord = ~d;
        unsigned u = (ord & 0x80000000u) ? (ord ^ 0x80000000u) : ~ord;
        float sc = __uint_as_float(u);
        size_t gi = (size_t)img * NTOT + idx;
        ((float4*)sel_boxes)[img * PRE_NMS + r] = ((const float4*)dec_boxes)[gi];
        sel_scores[img * PRE_NMS + r] = sc;
        sel_labels[img * PRE_NMS + r] = labels[gi];
    }
}

// ---------------------------------------------------------------------------
// Kernel 4: IoU suppression bitmask, TRANSPOSED layout [img][word][row].
// bit j of mask_t[img][w][row] = IoU(row, w*64+j) > 0.5 && w*64+j > row.
// ---------------------------------------------------------------------------
__global__ __launch_bounds__(256) void k_mask(const float* __restrict__ sel_boxes,
                                              u64* __restrict__ mask_t)
{
    int t = blockIdx.x * 256 + threadIdx.x;   // 4*16*1000 = 64000
    int img = t / 16000;
    int rem = t % 16000;
    int w   = rem / 1000;
    int row = rem % 1000;
    float4 br = ((const float4*)sel_boxes)[img * PRE_NMS + row];
    float ax1 = br.x, ay1 = br.y, ax2 = br.z, ay2 = br.w;
    float aarea = (ax2 - ax1) * (ay2 - ay1);
    u64 bits = 0;
    int j0 = w * 64;
    for (int jj = 0; jj < 64; jj++) {
        int j = j0 + jj;
        if (j >= PRE_NMS || j <= row) continue;
        float4 bb = ((const float4*)sel_boxes)[img * PRE_NMS + j];
        float ix1 = fmaxf(ax1, bb.x), iy1 = fmaxf(ay1, bb.y);
        float ix2 = fminf(ax2, bb.z), iy2 = fminf(ay2, bb.w);
        float iw = fmaxf(ix2 - ix1, 0.0f), ih = fmaxf(iy2 - iy1, 0.0f);
        float inter = iw * ih;
        float barea = (bb.z - bb.x) * (bb.w - bb.y);
        float uni = fmaxf(aarea + barea - inter, 1e-6f);
        if (inter / uni > 0.5f) bits |= 1ull << jj;
    }
    mask_t[t] = bits;   // t == ((img*16 + w)*1000 + row)
}

// ---------------------------------------------------------------------------
// Kernel 5: block-resolve NMS sweep, SALU serial chain.
// Wave 0 resolves; waves 1..3 double-buffer-stage the next mask column.
// Per 64-row block W:
//   step1 (VALU): lanes apply kept rows of resolved blocks to word W,
//                 OR-butterfly -> uniform suppression word.
//   step2 (SALU): 64 unrolled steps; ms fetched via v_readlane (off-chain),
//                 keep-word updates are wave-uniform scalar ops (~1 cyc each).
// ---------------------------------------------------------------------------
__global__ __launch_bounds__(256) void k_sweep(const u64* __restrict__ mask_t,
                                               const float* __restrict__ sel_boxes,
                                               const float* __restrict__ sel_scores,
                                               const int* __restrict__ sel_labels,
                                               float* __restrict__ out)
{
    __shared__ u64 col[2][1024];
    __shared__ u64 keepw[16];
    __shared__ int pcnt[17];
    int img = blockIdx.x;
    int tid = threadIdx.x;
    int lane = tid & 63;
    int wid = tid >> 6;
    const u64* mt = mask_t + (size_t)img * 16000;

    // prologue: stage column 0
    for (int i = tid; i < 1024; i += 256) col[0][i] = (i < PRE_NMS) ? mt[i] : 0ull;

    u64 kw[16];
    if (wid == 0) {
#pragma unroll
        for (int b = 0; b < 16; b++) {
            int slot = b * 64 + lane;
            float sc = (slot < PRE_NMS) ? sel_scores[img * PRE_NMS + slot] : -1.0f;
            kw[b] = __ballot(sc > 0.05f);
        }
    }
    __syncthreads();

#define SWEEP_STEP(W)                                                          \
    {                                                                          \
        if ((W) < 15 && wid != 0) {                                            \
            for (int i = tid - 64; i < 1024; i += 192)                         \
                col[((W) + 1) & 1][i] =                                        \
                    (i < PRE_NMS) ? mt[((W) + 1) * 1000 + i] : 0ull;           \
        }                                                                      \
        if (wid == 0) {                                                        \
            const u64* c = col[(W) & 1];                                       \
            u64 m_intra = c[(W) * 64 + lane];                                  \
            unsigned milo = (unsigned)(m_intra & 0xFFFFFFFFull);               \
            unsigned mihi = (unsigned)(m_intra >> 32);                         \
            u64 sup = 0;                                                       \
            _Pragma("unroll")                                                  \
            for (int b = 0; b < (W); b++) {                                    \
                u64 mrow = c[b * 64 + lane];                                   \
                u64 sel = 0ull - ((kw[b] >> lane) & 1ull);                     \
                sup |= mrow & sel;                                             \
            }                                                                  \
            if ((W) > 0) {                                                     \
                _Pragma("unroll")                                              \
                for (int d = 1; d < 64; d <<= 1) sup |= __shfl_xor(sup, d);    \
            }                                                                  \
            unsigned slo = __builtin_amdgcn_readfirstlane((unsigned)sup);      \
            unsigned shi = __builtin_amdgcn_readfirstlane((unsigned)(sup>>32));\
            u64 kwv = kw[(W)] & ~(((u64)shi << 32) | (u64)slo);                \
            _Pragma("unroll")                                                  \
            for (int ss = 0; ss < 64; ss++) {                                  \
                u64 ms = ((u64)(unsigned)__builtin_amdgcn_readlane(mihi, ss)   \
                          << 32)                                               \
                       | (u64)(unsigned)__builtin_amdgcn_readlane(milo, ss);   \
                u64 bit = (kwv >> ss) & 1ull;                                  \
                kwv &= ~(ms & (0ull - bit));                                   \
            }                                                                  \
            kw[(W)] = kwv;                                                     \
        }                                                                      \
        __syncthreads();                                                       \
    }

    SWEEP_STEP(0)  SWEEP_STEP(1)  SWEEP_STEP(2)  SWEEP_STEP(3)
    SWEEP_STEP(4)  SWEEP_STEP(5)  SWEEP_STEP(6)  SWEEP_STEP(7)
    SWEEP_STEP(8)  SWEEP_STEP(9)  SWEEP_STEP(10) SWEEP_STEP(11)
    SWEEP_STEP(12) SWEEP_STEP(13) SWEEP_STEP(14) SWEEP_STEP(15)
#undef SWEEP_STEP

    if (tid == 0) {
#pragma unroll
        for (int b = 0; b < 16; b++) keepw[b] = kw[b];
        int c = 0;
#pragma unroll
        for (int b = 0; b < 16; b++) { pcnt[b] = c; c += __popcll(kw[b]); }
        pcnt[16] = c;
    }
    __syncthreads();

    int nk = pcnt[16];
    // kept entries, in slot order, are exactly top_k(fs_all, 300)'s leading entries
    for (int slot = tid; slot < PRE_NMS; slot += 256) {
        u64 kv = keepw[slot >> 6];
        if ((kv >> (slot & 63)) & 1ull) {
            int rank = pcnt[slot >> 6] + __popcll(kv & ((1ull << (slot & 63)) - 1ull));
            if (rank < POST_NMS) {
                ((float4*)out)[img * POST_NMS + rank] =
                    ((const float4*)sel_boxes)[img * PRE_NMS + slot];
                out[NIMG * POST_NMS * 4 + img * POST_NMS + rank] =
                    sel_scores[img * PRE_NMS + slot];
                out[NIMG * POST_NMS * 5 + img * POST_NMS + rank] =
                    (float)sel_labels[img * PRE_NMS + slot];
            }
        }
    }
    // filler slots: box=0, score=-1, label=-1
    for (int r = tid; r < POST_NMS; r += 256) {
        if (r >= nk) {
            ((float4*)out)[img * POST_NMS + r] = make_float4(0.f, 0.f, 0.f, 0.f);
            out[NIMG * POST_NMS * 4 + img * POST_NMS + r] = -1.0f;
            out[NIMG * POST_NMS * 5 + img * POST_NMS + r] = -1.0f;
        }
    }
}

// ---------------------------------------------------------------------------
extern "C" void kernel_launch(void* const* d_in, const int* in_sizes, int n_in,
                              void* d_out, int out_size, void* d_ws, size_t ws_size,
                              hipStream_t stream)
{
    const float* b0 = (const float*)d_in[0];
    const float* s0 = (const float*)d_in[1];
    const float* r0 = (const float*)d_in[2];
    const float* b1 = (const float*)d_in[3];
    const float* s1 = (const float*)d_in[4];
    const float* r1 = (const float*)d_in[5];
    const float* b2 = (const float*)d_in[6];
    const float* s2 = (const float*)d_in[7];
    const float* r2 = (const float*)d_in[8];
    const float* b3 = (const float*)d_in[9];
    const float* s3 = (const float*)d_in[10];
    const float* r3 = (const float*)d_in[11];
    const float* b4 = (const float*)d_in[12];
    const float* s4 = (const float*)d_in[13];
    const float* r4 = (const float*)d_in[14];

    char* ws = (char*)d_ws;
    size_t off = 0;
    float* dec_boxes = (float*)(ws + off); off += (size_t)NIMG * NTOT * 4 * 4;
    int*   labels    = (int*)(ws + off);   off += (size_t)NIMG * NTOT * 4;
    off = (off + 15) & ~(size_t)15;
    u64* keysA = (u64*)(ws + off); off += (size_t)NIMG * NPAD * 8;
    u64* keysB = (u64*)(ws + off); off += (size_t)NIMG * 16384 * 8;
    float* sel_boxes  = (float*)(ws + off); off += (size_t)NIMG * PRE_NMS * 4 * 4;
    float* sel_scores = (float*)(ws + off); off += (size_t)NIMG * PRE_NMS * 4;
    int*   sel_labels = (int*)(ws + off);   off += (size_t)NIMG * PRE_NMS * 4;
    u64* mask_t = (u64*)(ws + off); off += (size_t)NIMG * 16 * PRE_NMS * 8;  // [img][word][row]

    float* out = (float*)d_out;

    k_decode<<<dim3((NIMG * NPAD) / 256), dim3(256), 0, stream>>>(
        b0, s0, r0, b1, s1, r1, b2, s2, r2, b3, s3, r3, b4, s4, r4,
        dec_boxes, labels, keysA);

    // 4-way ladder: 64 chunks -> 16 -> 4 -> 1 lists per image
    k_sortmerge4<<<dim3(NIMG * 16), dim3(256), 0, stream>>>(keysA, keysB, 16, 1);
    k_sortmerge4<<<dim3(NIMG * 4),  dim3(256), 0, stream>>>(keysB, keysA, 4, 0);
    k_sortmerge4<<<dim3(NIMG * 1),  dim3(256), 0, stream>>>(keysA, keysB, 1, 0);

    k_gather<<<dim3(NIMG), dim3(256), 0, stream>>>(keysB, dec_boxes, labels,
                                                   sel_boxes, sel_scores, sel_labels);

    k_mask<<<dim3((NIMG * 16 * PRE_NMS) / 256), dim3(256), 0, stream>>>(sel_boxes, mask_t);

    k_sweep<<<dim3(NIMG), dim3(256), 0, stream>>>(mask_t, sel_boxes, sel_scores, sel_labels, out);
}